// Round 4
// baseline (59.566 us; speedup 1.0000x reference)
//
#include <hip/hip_runtime.h>
#include <math.h>

#define B_      64
#define N_      153600      // C*H*W = 8*120*160
#define BPB     30          // 38400 float4 / 30 = 1280 / 256 thr = 5 iters exact
#define THREADS 256
#define CHUNK   (N_ / 4 / BPB)    // 1280 float4 per block
#define ITERS   (CHUNK / THREADS) // 5

typedef float vf4 __attribute__((ext_vector_type(4)));

// Stage 1: partial[b, blk, k] = sum over this block's contiguous chunk of
//          Jt[b,k,n] * w[b,n] * r[b,n].  Depth-2 software prefetch: iteration
//          j+1's 8 float4 loads are issued before iteration j's FMAs.
__global__ __launch_bounds__(THREADS) void jtr_partial_kernel(
    const float* __restrict__ Jt,     // (B, 6, N)
    const float* __restrict__ W,      // (B, N)
    const float* __restrict__ R,      // (B, N)
    float* __restrict__ partial)      // (B, BPB, 6)
{
    const int b   = blockIdx.x / BPB;
    const int blk = blockIdx.x % BPB;
    const int tid = threadIdx.x;

    const vf4* w4 = (const vf4*)(W + (size_t)b * N_);
    const vf4* r4 = (const vf4*)(R + (size_t)b * N_);
    const float* jt = Jt + (size_t)b * 6 * N_;
    const int i0 = blk * CHUNK + tid;

    float acc[6] = {0.f, 0.f, 0.f, 0.f, 0.f, 0.f};

    // prologue: load iteration 0
    vf4 wc = w4[i0];
    vf4 rc = r4[i0];
    vf4 jc[6];
#pragma unroll
    for (int k = 0; k < 6; ++k)
        jc[k] = ((const vf4*)(jt + (size_t)k * N_))[i0];

#pragma unroll
    for (int j = 0; j < ITERS; ++j) {
        vf4 wn, rn, jn[6];
        if (j + 1 < ITERS) {                 // compile-time under full unroll
            const int i = i0 + (j + 1) * THREADS;
            wn = w4[i];
            rn = r4[i];
#pragma unroll
            for (int k = 0; k < 6; ++k)
                jn[k] = ((const vf4*)(jt + (size_t)k * N_))[i];
        }
        const float wr0 = wc.x * rc.x, wr1 = wc.y * rc.y;
        const float wr2 = wc.z * rc.z, wr3 = wc.w * rc.w;
#pragma unroll
        for (int k = 0; k < 6; ++k)
            acc[k] += jc[k].x * wr0 + jc[k].y * wr1 + jc[k].z * wr2 + jc[k].w * wr3;
        if (j + 1 < ITERS) {
            wc = wn; rc = rn;
#pragma unroll
            for (int k = 0; k < 6; ++k) jc[k] = jn[k];
        }
    }

    // 64-lane wave reduction of the 6 accumulators
#pragma unroll
    for (int k = 0; k < 6; ++k) {
        float v = acc[k];
#pragma unroll
        for (int off = 32; off >= 1; off >>= 1) v += __shfl_down(v, off, 64);
        acc[k] = v;
    }

    __shared__ float smem[4][6];
    const int lane = tid & 63;
    const int wid  = tid >> 6;
    if (lane == 0) {
#pragma unroll
        for (int k = 0; k < 6; ++k) smem[wid][k] = acc[k];
    }
    __syncthreads();
    if (tid < 6) {
        partial[(size_t)(b * BPB + blk) * 6 + tid] =
            smem[0][tid] + smem[1][tid] + smem[2][tid] + smem[3][tid];
    }
}

// Stage 2: one block per batch. Threads t = k*32 + g (k<6, g<32) reduce the 30
// partials for component k via a width-32 shuffle tree; thread 0 runs the tiny
// 6x6 damped solve + Rodrigues + pose compose.
__global__ __launch_bounds__(256) void solve_kernel(
    const float* __restrict__ partial,   // (B, BPB, 6)
    const float* __restrict__ JtJ,       // (B, 6, 6)
    const float* __restrict__ poseR,     // (B, 3, 3)
    const float* __restrict__ poseT,     // (B, 3)
    float* __restrict__ out)             // R_new (B*9) then t_new (B*3)
{
    const int b = blockIdx.x;
    const int t = threadIdx.x;

    __shared__ float sums[6];
    const int k = t >> 5;        // component 0..7 (only <6 used)
    const int g = t & 31;        // lane in 32-group
    if (k < 6) {
        float v = (g < BPB) ? partial[(size_t)b * BPB * 6 + g * 6 + k] : 0.f;
#pragma unroll
        for (int off = 16; off >= 1; off >>= 1) v += __shfl_down(v, off, 32);
        if (g == 0) sums[k] = v;
    }
    __syncthreads();
    if (t != 0) return;

    // Hessian = JtJ + trace(JtJ)*1e-6 * I ; solve H xi = JtR
    const float* Hj = JtJ + (size_t)b * 36;
    const float tr = Hj[0] + Hj[7] + Hj[14] + Hj[21] + Hj[28] + Hj[35];
    float M[6][7];
#pragma unroll
    for (int i = 0; i < 6; ++i) {
#pragma unroll
        for (int j = 0; j < 6; ++j) M[i][j] = Hj[i * 6 + j];
        M[i][i] += tr * 1e-6f;
        M[i][6] = sums[i];
    }
    for (int col = 0; col < 6; ++col) {
        int piv = col; float best = fabsf(M[col][col]);
        for (int r = col + 1; r < 6; ++r) {
            float a = fabsf(M[r][col]);
            if (a > best) { best = a; piv = r; }
        }
        if (piv != col)
            for (int j = col; j < 7; ++j) { float tm = M[col][j]; M[col][j] = M[piv][j]; M[piv][j] = tm; }
        const float inv = 1.0f / M[col][col];
        for (int r = col + 1; r < 6; ++r) {
            const float f = M[r][col] * inv;
            for (int j = col; j < 7; ++j) M[r][j] -= f * M[col][j];
        }
    }
    float xi[6];
    for (int i = 5; i >= 0; --i) {
        float s = M[i][6];
        for (int j = i + 1; j < 6; ++j) s -= M[i][j] * xi[j];
        xi[i] = s / M[i][i];
    }

    // dR = twist2mat(-xi[:3]) = c*I + (1-c)*u u^T + s*K(u)
    const float wx = -xi[0], wy = -xi[1], wz = -xi[2];
    float th = fmaxf(sqrtf(wx * wx + wy * wy + wz * wz), 1e-12f);
    const float ux = wx / th, uy = wy / th, uz = wz / th;
    const float s = sinf(th), c = cosf(th), omc = 1.0f - c;
    float dR[3][3];
    dR[0][0] = c + omc * ux * ux;       dR[0][1] = omc * ux * uy - s * uz;  dR[0][2] = omc * ux * uz + s * uy;
    dR[1][0] = omc * uy * ux + s * uz;  dR[1][1] = c + omc * uy * uy;       dR[1][2] = omc * uy * uz - s * ux;
    dR[2][0] = omc * uz * ux - s * uy;  dR[2][1] = omc * uz * uy + s * ux;  dR[2][2] = c + omc * uz * uz;

    // dt = -(dR @ xi[3:])
    float dt[3];
#pragma unroll
    for (int i = 0; i < 3; ++i)
        dt[i] = -(dR[i][0] * xi[3] + dR[i][1] * xi[4] + dR[i][2] * xi[5]);

    // R_new = pose_R @ dR ; t_new = pose_R @ dt + pose_t
    const float* pR = poseR + (size_t)b * 9;
#pragma unroll
    for (int i = 0; i < 3; ++i) {
        const float p0 = pR[i * 3 + 0], p1 = pR[i * 3 + 1], p2 = pR[i * 3 + 2];
#pragma unroll
        for (int j = 0; j < 3; ++j)
            out[b * 9 + i * 3 + j] = p0 * dR[0][j] + p1 * dR[1][j] + p2 * dR[2][j];
        out[B_ * 9 + b * 3 + i] = p0 * dt[0] + p1 * dt[1] + p2 * dt[2] + poseT[b * 3 + i];
    }
}

extern "C" void kernel_launch(void* const* d_in, const int* in_sizes, int n_in,
                              void* d_out, int out_size, void* d_ws, size_t ws_size,
                              hipStream_t stream) {
    const float* JtJ     = (const float*)d_in[0];
    const float* Jt      = (const float*)d_in[1];
    const float* weights = (const float*)d_in[2];
    const float* R       = (const float*)d_in[3];
    const float* pose_R  = (const float*)d_in[4];
    const float* pose_t  = (const float*)d_in[5];
    // d_in[6..10] (invD0, invD1, x0, x1, K) unused by the reference.

    float* out     = (float*)d_out;
    float* partial = (float*)d_ws;   // B*BPB*6 floats = 45 KB

    jtr_partial_kernel<<<B_ * BPB, THREADS, 0, stream>>>(Jt, weights, R, partial);
    solve_kernel<<<B_, 256, 0, stream>>>(partial, JtJ, pose_R, pose_t, out);
}